// Round 10
// baseline (388.025 us; speedup 1.0000x reference)
//
#include <hip/hip_runtime.h>
#include <hip/hip_bf16.h>
#include <math.h>

typedef unsigned short ushort_t;
typedef unsigned int uint_t;
typedef __bf16 bf16x8 __attribute__((ext_vector_type(8)));
typedef float f32x4 __attribute__((ext_vector_type(4)));
typedef __fp16 fp16v2 __attribute__((ext_vector_type(2)));   // cvt_pkrtz result type
typedef _Float16 f16x4 __attribute__((ext_vector_type(4)));  // MFMA operand type

#define NSEQ 2048
// q pre-scale: HEAD_DIM^-0.5 * log2(e) so softmax runs in exp2 domain
#define QSCALE 0.3606737602222409f

__device__ __forceinline__ float exp2_fast(float x) {
#if __has_builtin(__builtin_amdgcn_exp2f)
    return __builtin_amdgcn_exp2f(x);
#else
    return exp2f(x);
#endif
}

union U8 { ushort_t u[8]; bf16x8 v; uint4 q; uint_t w[4]; };
union F8 { float f[8]; float4 v4[2]; };
union H4 { fp16v2 h2[2]; f16x4 v; uint_t w[2]; };
union HV { fp16v2 h2[4]; uint4 q; };

// pack two floats -> bf16x2 (v_cvt_pk_bf16_f32 on gfx950)
__device__ __forceinline__ uint_t pk2(float a, float b) {
    __hip_bfloat162 h2 = __float22bfloat162_rn(make_float2(a, b));
    union { __hip_bfloat162 h; uint_t u; } cv; cv.h = h2; return cv.u;
}

// split 8 fp32 into bf16 hi + bf16 lo (residual), packed
__device__ __forceinline__ void split8(const F8& x, U8& hi, U8& lo) {
#pragma unroll
    for (int p = 0; p < 4; ++p) {
        const float a = x.f[2*p], b = x.f[2*p+1];
        const uint_t hw = pk2(a, b);
        hi.w[p] = hw;
        const float ha = __uint_as_float(hw << 16);
        const float hb = __uint_as_float(hw & 0xFFFF0000u);
        lo.w[p] = pk2(a - ha, b - hb);
    }
}

// ---------------------------------------------------------------------------
// Kernel 0: pack Wq/Wk (A-frag order, hi/lo) and Wo (B-frag order, hi/lo).
// wpk[mat][((ct*4+f)*64+lane)*8+j] = W[ct*16+(lane&15)][f*32+(lane>>4)*8+j]
// Measured R8<->R9 A/B: packed fragment loads are worth ~10 us vs strided.
// ---------------------------------------------------------------------------
__global__ __launch_bounds__(256) void wpack_kernel(
    const float* __restrict__ Wq, const float* __restrict__ Wk,
    const float* __restrict__ Wo,
    ushort_t* __restrict__ wpk_hi, ushort_t* __restrict__ wpk_lo,
    ushort_t* __restrict__ wo_hi, ushort_t* __restrict__ wo_lo)
{
    const int idx = blockIdx.x * 256 + threadIdx.x;   // 0..4351
    if (idx < 4096) {
        const int lane = idx & 63;
        const int f    = (idx >> 6) & 3;
        const int ct   = (idx >> 8) & 7;
        const int mat  = idx >> 11;
        const float* W = mat ? Wk : Wq;
        const float* src = W + (size_t)(ct * 16 + (lane & 15)) * 128
                             + f * 32 + (lane >> 4) * 8;
        F8 x; x.v4[0] = *(const float4*)src; x.v4[1] = *(const float4*)(src + 4);
        U8 hi, lo;
        split8(x, hi, lo);
        const size_t dst = (size_t)mat * 16384 + ((size_t)(ct * 4 + f) * 64 + lane) * 8;
        *(uint4*)(wpk_hi + dst) = hi.q;
        *(uint4*)(wpk_lo + dst) = lo.q;
    } else if (idx < 4352) {
        const int i2   = idx - 4096;     // 0..255
        const int lane = i2 & 63;
        const int f    = i2 >> 6;        // 0..3
        const float* src = Wo + (size_t)(lane & 15) * 128
                              + f * 32 + (lane >> 4) * 8;
        F8 x; x.v4[0] = *(const float4*)src; x.v4[1] = *(const float4*)(src + 4);
        U8 hi, lo;
        split8(x, hi, lo);
        const size_t dst = ((size_t)f * 64 + lane) * 8;
        *(uint4*)(wo_hi + dst) = hi.q;
        *(uint4*)(wo_lo + dst) = lo.q;
    }
}

// ---------------------------------------------------------------------------
// Kernel 1: fused QKV projection, one dispatch.
// Blocks 0..2047: Q/K path, one wave = one (mat, head, 16-token) tile,
//   W from packed fragments (coalesced 16B/lane, L2-hot).
// Blocks 2048..2559: V path (VALU, K=16) + V^T store in f16.
// ---------------------------------------------------------------------------
__global__ __launch_bounds__(256, 4) void qkv_proj_kernel(
    const float* __restrict__ query, const float* __restrict__ key,
    const float* __restrict__ value,
    const float* __restrict__ bq, const float* __restrict__ bk,
    const float* __restrict__ Wv, const float* __restrict__ bv,
    const ushort_t* __restrict__ wpk_hi, const ushort_t* __restrict__ wpk_lo,
    ushort_t* __restrict__ q_hi, ushort_t* __restrict__ q_lo,
    ushort_t* __restrict__ k_hi, ushort_t* __restrict__ k_lo,
    ushort_t* __restrict__ vt)
{
    const int t = threadIdx.x;
    if (blockIdx.x < 2048) {
        const int w   = t >> 6;
        const int l   = t & 63;
        const int col = l & 15;
        const int g   = l >> 4;

        const int gw  = blockIdx.x * 4 + w;   // 0..8191
        const int mat = gw & 1;               // 0 = Q, 1 = K
        const int h   = (gw >> 1) & 7;        // head
        const int T   = gw >> 4;              // token tile
        const int rbase = T * 16;
        const int b = rbase >> 11;

        // B fragments from X: token rbase+col, k = f*32 + g*8 + j
        const float* X = mat ? key : query;
        const float* xrow = X + (size_t)(rbase + col) * 128 + g * 8;
        bf16x8 xh[4], xl[4];
#pragma unroll
        for (int f = 0; f < 4; ++f) {
            F8 x;
            x.v4[0] = *(const float4*)(xrow + f * 32);
            x.v4[1] = *(const float4*)(xrow + f * 32 + 4);
            U8 hi, lo;
            split8(x, hi, lo);
            xh[f] = hi.v; xl[f] = lo.v;
        }

        // A fragments from packed W (coalesced 16B/lane)
        bf16x8 whf[4], wlf[4];
#pragma unroll
        for (int f = 0; f < 4; ++f) {
            const size_t o = (size_t)mat * 16384 + ((size_t)(h * 4 + f) * 64 + l) * 8;
            whf[f] = *(const bf16x8*)(wpk_hi + o);
            wlf[f] = *(const bf16x8*)(wpk_lo + o);
        }

        const float* bias = mat ? bk : bq;
        const float4 b4 = *(const float4*)(bias + h * 16 + 4 * g);
        f32x4 acc = {b4.x, b4.y, b4.z, b4.w};
#pragma unroll
        for (int f = 0; f < 4; ++f) {
            acc = __builtin_amdgcn_mfma_f32_16x16x32_bf16(whf[f], xh[f], acc, 0, 0, 0);
            acc = __builtin_amdgcn_mfma_f32_16x16x32_bf16(wlf[f], xh[f], acc, 0, 0, 0);
            acc = __builtin_amdgcn_mfma_f32_16x16x32_bf16(whf[f], xl[f], acc, 0, 0, 0);
        }

        ushort_t* dhi = mat ? k_hi : q_hi;
        ushort_t* dlo = mat ? k_lo : q_lo;
        const float scale = mat ? 1.0f : QSCALE;
        const int tok = (rbase & 2047) + col;
        const size_t abase = ((size_t)(b * 8 + h) * NSEQ + tok) * 16 + 4 * g;
        const float a0 = acc[0]*scale, a1 = acc[1]*scale;
        const float a2 = acc[2]*scale, a3 = acc[3]*scale;
        const uint_t h01 = pk2(a0, a1), h23 = pk2(a2, a3);
        const uint_t l01 = pk2(a0 - __uint_as_float(h01 << 16),
                               a1 - __uint_as_float(h01 & 0xFFFF0000u));
        const uint_t l23 = pk2(a2 - __uint_as_float(h23 << 16),
                               a3 - __uint_as_float(h23 & 0xFFFF0000u));
        uint2 sh; sh.x = h01; sh.y = h23;
        uint2 sl; sl.x = l01; sl.y = l23;
        *(uint2*)(dhi + abase) = sh;
        *(uint2*)(dlo + abase) = sl;
    } else {
        // ---- V path ----
        const int rbase = (blockIdx.x - 2048) * 16;
        const int b = rbase >> 11;
        const int e  = t & 127;
        const int rh = t >> 7;
        const int r0 = rbase + rh * 8;
        const float4* Wv4 = (const float4*)(Wv + (size_t)e * 16);
        const float4 wv0 = Wv4[0], wv1 = Wv4[1], wv2 = Wv4[2], wv3 = Wv4[3];
        const float bvv = bv[e];
        F8 af;
#pragma unroll
        for (int r = 0; r < 8; ++r) {
            const float4* xv4 = (const float4*)(value + (size_t)(r0 + r) * 16);
            const float4 x0 = xv4[0], x1 = xv4[1], x2 = xv4[2], x3 = xv4[3];
            float a = bvv;
            a += wv0.x*x0.x + wv0.y*x0.y + wv0.z*x0.z + wv0.w*x0.w;
            a += wv1.x*x1.x + wv1.y*x1.y + wv1.z*x1.z + wv1.w*x1.w;
            a += wv2.x*x2.x + wv2.y*x2.y + wv2.z*x2.z + wv2.w*x2.w;
            a += wv3.x*x3.x + wv3.y*x3.y + wv3.z*x3.z + wv3.w*x3.w;
            af.f[r] = a;
        }
        HV vpk;
#pragma unroll
        for (int p = 0; p < 4; ++p)
            vpk.h2[p] = __builtin_amdgcn_cvt_pkrtz(af.f[2*p], af.f[2*p+1]);
        const int hv = e >> 4, dd = e & 15;
        *(uint4*)(vt + ((size_t)(b * 8 + hv) * 16 + dd) * NSEQ + (r0 & 2047)) = vpk.q;
    }
}

// ---------------------------------------------------------------------------
// Kernel 2: fused two-phase flash attention, 4-way split-K.
// Block: 32 q rows x 2048 keys; wave kh = key quarter (512 keys), 2 q
// subtiles per wave. grid 2048 (XCD-local swizzle), launch_bounds(256,8)
// -> 8 blocks/CU, 32 resident waves (vs R9's 16): directly attacks the
// ~60% no-issue stall fraction. Per-wave loop body identical to R9 (best).
// ---------------------------------------------------------------------------
__global__ __launch_bounds__(256, 8) void attn_kernel(
    const ushort_t* __restrict__ q_hi, const ushort_t* __restrict__ q_lo,
    const ushort_t* __restrict__ k_hi, const ushort_t* __restrict__ k_lo,
    const ushort_t* __restrict__ vt, ushort_t* __restrict__ ctxb)
{
    const int t    = threadIdx.x;
    const int w    = t >> 6;           // wave = key quarter kh
    const int l    = t & 63;
    const int col  = l & 15;
    const int g    = l >> 4;

    // XCD-aware decode: bh's 64 q-blocks all have id % 8 == bh % 8
    const int id   = blockIdx.x;       // 0..2047
    const int rest = id >> 3;          // 0..255
    const int bh   = (rest >> 6) * 8 + (id & 7);
    const int qbase = (rest & 63) * 32;

    __shared__ float lds_m[4][32];
    __shared__ __align__(16) float lds_o[3][2][16][16];
    __shared__ float lds_l[3][2][16];

    U8 Uz;
#pragma unroll
    for (int i = 0; i < 8; ++i) Uz.u[i] = 0;
    const bf16x8 zf = Uz.v;

    // Q fragments for 2 subtiles: b1=[qhi|qhi], b2=[qlo|0]
    bf16x8 bq1[2], bq2[2];
#pragma unroll
    for (int s = 0; s < 2; ++s) {
        const size_t qoff = ((size_t)(bh * NSEQ + qbase + s * 16 + col)) * 16 + (g & 1) * 8;
        bq1[s] = *(const bf16x8*)(q_hi + qoff);
        const bf16x8 t2 = *(const bf16x8*)(q_lo + qoff);
        bq2[s] = (g < 2) ? t2 : zf;
    }

    const ushort_t* ksel = (g < 2) ? k_hi : k_lo;
    const ushort_t* aptr = ksel + ((size_t)bh * NSEQ + col) * 16 + (g & 1) * 8
                         + (size_t)w * (512 * 16);
    const ushort_t* vp = vt + ((size_t)bh * 16 + col) * NSEQ + w * 512;

    // ---- Phase 1: max over this wave's 512 keys, both subtiles ----
    float m0 = -INFINITY, m1 = -INFINITY;
    const f32x4 z = {0.f, 0.f, 0.f, 0.f};
    bf16x8 pa1[2], pa2[2];
    pa1[0] = *(const bf16x8*)(aptr);
    pa2[0] = *(const bf16x8*)(aptr + 256);
    pa1[1] = *(const bf16x8*)(aptr + 512);
    pa2[1] = *(const bf16x8*)(aptr + 768);
#pragma unroll 2
    for (int kb = 0; kb < 16; ++kb) {
        const bf16x8 c1 = pa1[kb & 1], c2 = pa2[kb & 1];
        const int kn = (kb + 2) & 15;          // wrap: reloads kb 0,1 at the end
        pa1[kb & 1] = *(const bf16x8*)(aptr + (size_t)kn * 512);
        pa2[kb & 1] = *(const bf16x8*)(aptr + (size_t)kn * 512 + 256);
        const f32x4 s1 = __builtin_amdgcn_mfma_f32_16x16x32_bf16(c1, bq1[0], z, 0, 0, 0);
        const f32x4 s2 = __builtin_amdgcn_mfma_f32_16x16x32_bf16(c2, bq1[0], z, 0, 0, 0);
        const f32x4 s3 = __builtin_amdgcn_mfma_f32_16x16x32_bf16(c1, bq1[1], z, 0, 0, 0);
        const f32x4 s4 = __builtin_amdgcn_mfma_f32_16x16x32_bf16(c2, bq1[1], z, 0, 0, 0);
        m0 = fmaxf(m0, fmaxf(fmaxf(s1[0], s1[1]), fmaxf(s1[2], s1[3])));
        m0 = fmaxf(m0, fmaxf(fmaxf(s2[0], s2[1]), fmaxf(s2[2], s2[3])));
        m1 = fmaxf(m1, fmaxf(fmaxf(s3[0], s3[1]), fmaxf(s3[2], s3[3])));
        m1 = fmaxf(m1, fmaxf(fmaxf(s4[0], s4[1]), fmaxf(s4[2], s4[3])));
    }
    m0 = fmaxf(m0, __shfl_xor(m0, 16)); m0 = fmaxf(m0, __shfl_xor(m0, 32));
    m1 = fmaxf(m1, __shfl_xor(m1, 16)); m1 = fmaxf(m1, __shfl_xor(m1, 32));
    if (l < 32) lds_m[w][l] = (l < 16) ? m0 : m1;
    __syncthreads();
    const float mf0 = fmaxf(fmaxf(lds_m[0][col],      lds_m[1][col]),
                            fmaxf(lds_m[2][col],      lds_m[3][col]));
    const float mf1 = fmaxf(fmaxf(lds_m[0][col + 16], lds_m[1][col + 16]),
                            fmaxf(lds_m[2][col + 16], lds_m[3][col + 16]));
    const f32x4 zin0 = {-mf0, -mf0, -mf0, -mf0};
    const f32x4 zin1 = {-mf1, -mf1, -mf1, -mf1};

    // ---- Phase 2: exp-sum + PV (pa slots already hold kb=0,1) ----
    f32x4 o0 = {0.f,0.f,0.f,0.f}, o1 = {0.f,0.f,0.f,0.f};
    float ls0 = 0.f, ls1 = 0.f;
    f16x4 pv1[2], pv2[2];
    pv1[0] = *(const f16x4*)(vp + g * 4);
    pv2[0] = *(const f16x4*)(vp + 16 + g * 4);
    pv1[1] = *(const f16x4*)(vp + 32 + g * 4);
    pv2[1] = *(const f16x4*)(vp + 48 + g * 4);

#pragma unroll 2
    for (int kb = 0; kb < 16; ++kb) {
        const bf16x8 c1 = pa1[kb & 1], c2 = pa2[kb & 1];
        const f16x4 v1 = pv1[kb & 1], v2 = pv2[kb & 1];
        const int kn = (kb + 2) & 15;
        pa1[kb & 1] = *(const bf16x8*)(aptr + (size_t)kn * 512);
        pa2[kb & 1] = *(const bf16x8*)(aptr + (size_t)kn * 512 + 256);
        pv1[kb & 1] = *(const f16x4*)(vp + kn * 32 + g * 4);
        pv2[kb & 1] = *(const f16x4*)(vp + kn * 32 + 16 + g * 4);

        // subtile 0
        {
            f32x4 st1 = __builtin_amdgcn_mfma_f32_16x16x32_bf16(c1, bq2[0], zin0, 0, 0, 0);
            st1       = __builtin_amdgcn_mfma_f32_16x16x32_bf16(c1, bq1[0], st1, 0, 0, 0);
            f32x4 st2 = __builtin_amdgcn_mfma_f32_16x16x32_bf16(c2, bq2[0], zin0, 0, 0, 0);
            st2       = __builtin_amdgcn_mfma_f32_16x16x32_bf16(c2, bq1[0], st2, 0, 0, 0);
            const float p0 = exp2_fast(st1[0]), p1 = exp2_fast(st1[1]);
            const float p2 = exp2_fast(st1[2]), p3 = exp2_fast(st1[3]);
            const float p4 = exp2_fast(st2[0]), p5 = exp2_fast(st2[1]);
            const float p6 = exp2_fast(st2[2]), p7 = exp2_fast(st2[3]);
            ls0 += ((p0 + p1) + (p2 + p3)) + ((p4 + p5) + (p6 + p7));
            H4 b1u, b2u;
            b1u.h2[0] = __builtin_amdgcn_cvt_pkrtz(p0, p1);
            b1u.h2[1] = __builtin_amdgcn_cvt_pkrtz(p2, p3);
            b2u.h2[0] = __builtin_amdgcn_cvt_pkrtz(p4, p5);
            b2u.h2[1] = __builtin_amdgcn_cvt_pkrtz(p6, p7);
            o0 = __builtin_amdgcn_mfma_f32_16x16x16f16(v1, b1u.v, o0, 0, 0, 0);
            o0 = __builtin_amdgcn_mfma_f32_16x16x16f16(v2, b2u.v, o0, 0, 0, 0);
        }
        // subtile 1
        {
            f32x4 st1 = __builtin_amdgcn_mfma_f32_16x16x32_bf16(c1, bq2[1], zin1, 0, 0, 0);
            st1       = __builtin_amdgcn_mfma_f32_16x16x32_bf16(c1, bq1[1], st1, 0, 0, 0);
            f32x4 st2 = __builtin_amdgcn_mfma_f32_16x16x32_bf16(c2, bq2[1], zin1, 0, 0, 0);
            st2       = __builtin_amdgcn_mfma_f32_16x16x32_bf16(c2, bq1[1], st2, 0, 0, 0);
            const float p0 = exp2_fast(st1[0]), p1 = exp2_fast(st1[1]);
            const float p2 = exp2_fast(st1[2]), p3 = exp2_fast(st1[3]);
            const float p4 = exp2_fast(st2[0]), p5 = exp2_fast(st2[1]);
            const float p6 = exp2_fast(st2[2]), p7 = exp2_fast(st2[3]);
            ls1 += ((p0 + p1) + (p2 + p3)) + ((p4 + p5) + (p6 + p7));
            H4 b1u, b2u;
            b1u.h2[0] = __builtin_amdgcn_cvt_pkrtz(p0, p1);
            b1u.h2[1] = __builtin_amdgcn_cvt_pkrtz(p2, p3);
            b2u.h2[0] = __builtin_amdgcn_cvt_pkrtz(p4, p5);
            b2u.h2[1] = __builtin_amdgcn_cvt_pkrtz(p6, p7);
            o1 = __builtin_amdgcn_mfma_f32_16x16x16f16(v1, b1u.v, o1, 0, 0, 0);
            o1 = __builtin_amdgcn_mfma_f32_16x16x16f16(v2, b2u.v, o1, 0, 0, 0);
        }
    }

    ls0 += __shfl_xor(ls0, 16); ls0 += __shfl_xor(ls0, 32);
    ls1 += __shfl_xor(ls1, 16); ls1 += __shfl_xor(ls1, 32);

    // ---- Combine the four key-quarters (exact: same m) ----
    if (w > 0) {
        *(f32x4*)&lds_o[w - 1][0][col][4 * g] = o0;
        *(f32x4*)&lds_o[w - 1][1][col][4 * g] = o1;
        if (l < 32) lds_l[w - 1][l >> 4][col] = (l < 16) ? ls0 : ls1;
    }
    __syncthreads();
    if (w == 0) {
        const int b = bh >> 3, h = bh & 7;
#pragma unroll
        for (int s = 0; s < 2; ++s) {
            f32x4 oa = s ? o1 : o0;
            float lt = s ? ls1 : ls0;
#pragma unroll
            for (int j = 0; j < 3; ++j) {
                const f32x4 ob = *(const f32x4*)&lds_o[j][s][col][4 * g];
                oa[0] += ob[0]; oa[1] += ob[1]; oa[2] += ob[2]; oa[3] += ob[3];
                lt += lds_l[j][s][col];
            }
            const float li = 1.0f / lt;
            uint2 pkd;
            pkd.x = pk2(oa[0] * li, oa[1] * li);
            pkd.y = pk2(oa[2] * li, oa[3] * li);
            *(uint2*)(ctxb + ((size_t)(b * NSEQ + qbase + s * 16 + col)) * 128
                      + h * 16 + 4 * g) = pkd;
        }
    }
}

// ---------------------------------------------------------------------------
// Kernel 3: output projection on MFMA (packed split-bf16 Wo).
// 512 single-wave blocks: wave -> 16 rows.
// ---------------------------------------------------------------------------
__global__ __launch_bounds__(64) void outproj_kernel(
    const ushort_t* __restrict__ ctxb,
    const ushort_t* __restrict__ wo_hi, const ushort_t* __restrict__ wo_lo,
    const float* __restrict__ bo, float* __restrict__ out)
{
    const int l   = threadIdx.x;
    const int col = l & 15;
    const int g   = l >> 4;
    const int row0 = blockIdx.x * 16;

    const float bval = bo[col];
    f32x4 acc = {bval, bval, bval, bval};
    const ushort_t* ar = ctxb + (size_t)(row0 + col) * 128 + g * 8;
#pragma unroll
    for (int f = 0; f < 4; ++f) {
        const bf16x8 a = *(const bf16x8*)(ar + f * 32);
        const size_t o = ((size_t)f * 64 + l) * 8;
        const bf16x8 bh_ = *(const bf16x8*)(wo_hi + o);
        const bf16x8 bl_ = *(const bf16x8*)(wo_lo + o);
        acc = __builtin_amdgcn_mfma_f32_16x16x32_bf16(a, bh_, acc, 0, 0, 0);
        acc = __builtin_amdgcn_mfma_f32_16x16x32_bf16(a, bl_, acc, 0, 0, 0);
    }
#pragma unroll
    for (int r = 0; r < 4; ++r)
        out[(size_t)(row0 + 4 * g + r) * 16 + col] = acc[r];
}

// ---------------------------------------------------------------------------
extern "C" void kernel_launch(void* const* d_in, const int* in_sizes, int n_in,
                              void* d_out, int out_size, void* d_ws, size_t ws_size,
                              hipStream_t stream)
{
    const float* query = (const float*)d_in[0];
    const float* key_  = (const float*)d_in[1];
    const float* value = (const float*)d_in[2];
    const float* Wq = (const float*)d_in[3];
    const float* bq = (const float*)d_in[4];
    const float* Wk = (const float*)d_in[5];
    const float* bk = (const float*)d_in[6];
    const float* Wv = (const float*)d_in[7];
    const float* bv = (const float*)d_in[8];
    const float* Wo = (const float*)d_in[9];
    const float* bo = (const float*)d_in[10];
    float* out = (float*)d_out;

    ushort_t* base = (ushort_t*)d_ws;
    ushort_t* q_hi = base;
    ushort_t* q_lo = base + (1u << 20);
    ushort_t* k_hi = base + (2u << 20);
    ushort_t* k_lo = base + (3u << 20);
    ushort_t* vt   = base + (4u << 20);
    ushort_t* ctxb = base + (5u << 20);
    ushort_t* wpk_hi = base + (6u << 20);
    ushort_t* wpk_lo = wpk_hi + 32768;
    ushort_t* wo_hi  = wpk_hi + 65536;
    ushort_t* wo_lo  = wo_hi + 2048;

    wpack_kernel<<<dim3(17), dim3(256), 0, stream>>>(
        Wq, Wk, Wo, wpk_hi, wpk_lo, wo_hi, wo_lo);
    qkv_proj_kernel<<<dim3(2560), dim3(256), 0, stream>>>(
        query, key_, value, bq, bk, Wv, bv, wpk_hi, wpk_lo,
        q_hi, q_lo, k_hi, k_lo, vt);
    attn_kernel<<<dim3(2048), dim3(256), 0, stream>>>(
        q_hi, q_lo, k_hi, k_lo, vt, ctxb);
    outproj_kernel<<<dim3(512), dim3(64), 0, stream>>>(
        ctxb, wo_hi, wo_lo, bo, out);
}

// Round 11
// 143.498 us; speedup vs baseline: 2.7040x; 2.7040x over previous
//
#include <hip/hip_runtime.h>
#include <hip/hip_bf16.h>
#include <math.h>

typedef unsigned short ushort_t;
typedef unsigned int uint_t;
typedef __bf16 bf16x8 __attribute__((ext_vector_type(8)));
typedef float f32x4 __attribute__((ext_vector_type(4)));
typedef __fp16 fp16v2 __attribute__((ext_vector_type(2)));   // cvt_pkrtz result type
typedef _Float16 f16x4 __attribute__((ext_vector_type(4)));  // MFMA operand type

#define NSEQ 2048
// q pre-scale: HEAD_DIM^-0.5 * log2(e) so softmax runs in exp2 domain
#define QSCALE 0.3606737602222409f

__device__ __forceinline__ float exp2_fast(float x) {
#if __has_builtin(__builtin_amdgcn_exp2f)
    return __builtin_amdgcn_exp2f(x);
#else
    return exp2f(x);
#endif
}

union U8 { ushort_t u[8]; bf16x8 v; uint4 q; uint_t w[4]; };
union F8 { float f[8]; float4 v4[2]; };
union H4 { fp16v2 h2[2]; f16x4 v; uint_t w[2]; };
union HV { fp16v2 h2[4]; uint4 q; };

// pack two floats -> bf16x2 (v_cvt_pk_bf16_f32 on gfx950)
__device__ __forceinline__ uint_t pk2(float a, float b) {
    __hip_bfloat162 h2 = __float22bfloat162_rn(make_float2(a, b));
    union { __hip_bfloat162 h; uint_t u; } cv; cv.h = h2; return cv.u;
}

// split 8 fp32 into bf16 hi + bf16 lo (residual), packed
__device__ __forceinline__ void split8(const F8& x, U8& hi, U8& lo) {
#pragma unroll
    for (int p = 0; p < 4; ++p) {
        const float a = x.f[2*p], b = x.f[2*p+1];
        const uint_t hw = pk2(a, b);
        hi.w[p] = hw;
        const float ha = __uint_as_float(hw << 16);
        const float hb = __uint_as_float(hw & 0xFFFF0000u);
        lo.w[p] = pk2(a - ha, b - hb);
    }
}

// ---------------------------------------------------------------------------
// Kernel 0: pack Wq/Wk (A-frag order, hi/lo) and Wo (B-frag order, hi/lo).
// wpk[mat][((ct*4+f)*64+lane)*8+j] = W[ct*16+(lane&15)][f*32+(lane>>4)*8+j]
// ---------------------------------------------------------------------------
__global__ __launch_bounds__(256) void wpack_kernel(
    const float* __restrict__ Wq, const float* __restrict__ Wk,
    const float* __restrict__ Wo,
    ushort_t* __restrict__ wpk_hi, ushort_t* __restrict__ wpk_lo,
    ushort_t* __restrict__ wo_hi, ushort_t* __restrict__ wo_lo)
{
    const int idx = blockIdx.x * 256 + threadIdx.x;   // 0..4351
    if (idx < 4096) {
        const int lane = idx & 63;
        const int f    = (idx >> 6) & 3;
        const int ct   = (idx >> 8) & 7;
        const int mat  = idx >> 11;
        const float* W = mat ? Wk : Wq;
        const float* src = W + (size_t)(ct * 16 + (lane & 15)) * 128
                             + f * 32 + (lane >> 4) * 8;
        F8 x; x.v4[0] = *(const float4*)src; x.v4[1] = *(const float4*)(src + 4);
        U8 hi, lo;
        split8(x, hi, lo);
        const size_t dst = (size_t)mat * 16384 + ((size_t)(ct * 4 + f) * 64 + lane) * 8;
        *(uint4*)(wpk_hi + dst) = hi.q;
        *(uint4*)(wpk_lo + dst) = lo.q;
    } else if (idx < 4352) {
        const int i2   = idx - 4096;     // 0..255
        const int lane = i2 & 63;
        const int f    = i2 >> 6;        // 0..3
        const float* src = Wo + (size_t)(lane & 15) * 128
                              + f * 32 + (lane >> 4) * 8;
        F8 x; x.v4[0] = *(const float4*)src; x.v4[1] = *(const float4*)(src + 4);
        U8 hi, lo;
        split8(x, hi, lo);
        const size_t dst = ((size_t)f * 64 + lane) * 8;
        *(uint4*)(wo_hi + dst) = hi.q;
        *(uint4*)(wo_lo + dst) = lo.q;
    }
}

// ---------------------------------------------------------------------------
// Kernel 1: fused QKV projection, one dispatch.
// Blocks 0..2047: Q/K path, one wave = one (mat, head, 16-token) tile,
//   W from packed fragments (coalesced 16B/lane, L2-hot).
// Blocks 2048..2559: V path (VALU, K=16) + V^T store in f16.
// ---------------------------------------------------------------------------
__global__ __launch_bounds__(256, 4) void qkv_proj_kernel(
    const float* __restrict__ query, const float* __restrict__ key,
    const float* __restrict__ value,
    const float* __restrict__ bq, const float* __restrict__ bk,
    const float* __restrict__ Wv, const float* __restrict__ bv,
    const ushort_t* __restrict__ wpk_hi, const ushort_t* __restrict__ wpk_lo,
    ushort_t* __restrict__ q_hi, ushort_t* __restrict__ q_lo,
    ushort_t* __restrict__ k_hi, ushort_t* __restrict__ k_lo,
    ushort_t* __restrict__ vt)
{
    const int t = threadIdx.x;
    if (blockIdx.x < 2048) {
        const int w   = t >> 6;
        const int l   = t & 63;
        const int col = l & 15;
        const int g   = l >> 4;

        const int gw  = blockIdx.x * 4 + w;   // 0..8191
        const int mat = gw & 1;               // 0 = Q, 1 = K
        const int h   = (gw >> 1) & 7;        // head
        const int T   = gw >> 4;              // token tile
        const int rbase = T * 16;
        const int b = rbase >> 11;

        // B fragments from X: token rbase+col, k = f*32 + g*8 + j
        const float* X = mat ? key : query;
        const float* xrow = X + (size_t)(rbase + col) * 128 + g * 8;
        bf16x8 xh[4], xl[4];
#pragma unroll
        for (int f = 0; f < 4; ++f) {
            F8 x;
            x.v4[0] = *(const float4*)(xrow + f * 32);
            x.v4[1] = *(const float4*)(xrow + f * 32 + 4);
            U8 hi, lo;
            split8(x, hi, lo);
            xh[f] = hi.v; xl[f] = lo.v;
        }

        // A fragments from packed W (coalesced 16B/lane)
        bf16x8 whf[4], wlf[4];
#pragma unroll
        for (int f = 0; f < 4; ++f) {
            const size_t o = (size_t)mat * 16384 + ((size_t)(h * 4 + f) * 64 + l) * 8;
            whf[f] = *(const bf16x8*)(wpk_hi + o);
            wlf[f] = *(const bf16x8*)(wpk_lo + o);
        }

        const float* bias = mat ? bk : bq;
        const float4 b4 = *(const float4*)(bias + h * 16 + 4 * g);
        f32x4 acc = {b4.x, b4.y, b4.z, b4.w};
#pragma unroll
        for (int f = 0; f < 4; ++f) {
            acc = __builtin_amdgcn_mfma_f32_16x16x32_bf16(whf[f], xh[f], acc, 0, 0, 0);
            acc = __builtin_amdgcn_mfma_f32_16x16x32_bf16(wlf[f], xh[f], acc, 0, 0, 0);
            acc = __builtin_amdgcn_mfma_f32_16x16x32_bf16(whf[f], xl[f], acc, 0, 0, 0);
        }

        ushort_t* dhi = mat ? k_hi : q_hi;
        ushort_t* dlo = mat ? k_lo : q_lo;
        const float scale = mat ? 1.0f : QSCALE;
        const int tok = (rbase & 2047) + col;
        const size_t abase = ((size_t)(b * 8 + h) * NSEQ + tok) * 16 + 4 * g;
        const float a0 = acc[0]*scale, a1 = acc[1]*scale;
        const float a2 = acc[2]*scale, a3 = acc[3]*scale;
        const uint_t h01 = pk2(a0, a1), h23 = pk2(a2, a3);
        const uint_t l01 = pk2(a0 - __uint_as_float(h01 << 16),
                               a1 - __uint_as_float(h01 & 0xFFFF0000u));
        const uint_t l23 = pk2(a2 - __uint_as_float(h23 << 16),
                               a3 - __uint_as_float(h23 & 0xFFFF0000u));
        uint2 sh; sh.x = h01; sh.y = h23;
        uint2 sl; sl.x = l01; sl.y = l23;
        *(uint2*)(dhi + abase) = sh;
        *(uint2*)(dlo + abase) = sl;
    } else {
        // ---- V path ----
        const int rbase = (blockIdx.x - 2048) * 16;
        const int b = rbase >> 11;
        const int e  = t & 127;
        const int rh = t >> 7;
        const int r0 = rbase + rh * 8;
        const float4* Wv4 = (const float4*)(Wv + (size_t)e * 16);
        const float4 wv0 = Wv4[0], wv1 = Wv4[1], wv2 = Wv4[2], wv3 = Wv4[3];
        const float bvv = bv[e];
        F8 af;
#pragma unroll
        for (int r = 0; r < 8; ++r) {
            const float4* xv4 = (const float4*)(value + (size_t)(r0 + r) * 16);
            const float4 x0 = xv4[0], x1 = xv4[1], x2 = xv4[2], x3 = xv4[3];
            float a = bvv;
            a += wv0.x*x0.x + wv0.y*x0.y + wv0.z*x0.z + wv0.w*x0.w;
            a += wv1.x*x1.x + wv1.y*x1.y + wv1.z*x1.z + wv1.w*x1.w;
            a += wv2.x*x2.x + wv2.y*x2.y + wv2.z*x2.z + wv2.w*x2.w;
            a += wv3.x*x3.x + wv3.y*x3.y + wv3.z*x3.z + wv3.w*x3.w;
            af.f[r] = a;
        }
        HV vpk;
#pragma unroll
        for (int p = 0; p < 4; ++p)
            vpk.h2[p] = __builtin_amdgcn_cvt_pkrtz(af.f[2*p], af.f[2*p+1]);
        const int hv = e >> 4, dd = e & 15;
        *(uint4*)(vt + ((size_t)(b * 8 + hv) * 16 + dd) * NSEQ + (r0 & 2047)) = vpk.q;
    }
}

// ---------------------------------------------------------------------------
// Kernel 2: fused two-phase flash attention, 4-way split-K.
// Block: 32 q rows x 2048 keys; wave = key quarter (512 keys), 2 q subtiles.
// grid 2048 (XCD-local swizzle). launch_bounds(256,4): permissive bound --
// compiler keeps ~60 VGPR (R10's (256,8) forced 32 VGPR -> 1.2 GB spill
// traffic); at <=64 VGPR the HW packs 8 blocks/CU naturally.
// ---------------------------------------------------------------------------
__global__ __launch_bounds__(256, 4) void attn_kernel(
    const ushort_t* __restrict__ q_hi, const ushort_t* __restrict__ q_lo,
    const ushort_t* __restrict__ k_hi, const ushort_t* __restrict__ k_lo,
    const ushort_t* __restrict__ vt, ushort_t* __restrict__ ctxb)
{
    const int t    = threadIdx.x;
    const int w    = t >> 6;           // wave = key quarter kh
    const int l    = t & 63;
    const int col  = l & 15;
    const int g    = l >> 4;

    // XCD-aware decode: bh's 64 q-blocks all have id % 8 == bh % 8
    const int id   = blockIdx.x;       // 0..2047
    const int rest = id >> 3;          // 0..255
    const int bh   = (rest >> 6) * 8 + (id & 7);
    const int qbase = (rest & 63) * 32;

    __shared__ float lds_m[4][32];
    __shared__ __align__(16) float lds_o[3][2][16][16];
    __shared__ float lds_l[3][2][16];

    U8 Uz;
#pragma unroll
    for (int i = 0; i < 8; ++i) Uz.u[i] = 0;
    const bf16x8 zf = Uz.v;

    // Q fragments for 2 subtiles: b1=[qhi|qhi], b2=[qlo|0]
    bf16x8 bq1[2], bq2[2];
#pragma unroll
    for (int s = 0; s < 2; ++s) {
        const size_t qoff = ((size_t)(bh * NSEQ + qbase + s * 16 + col)) * 16 + (g & 1) * 8;
        bq1[s] = *(const bf16x8*)(q_hi + qoff);
        const bf16x8 t2 = *(const bf16x8*)(q_lo + qoff);
        bq2[s] = (g < 2) ? t2 : zf;
    }

    const ushort_t* ksel = (g < 2) ? k_hi : k_lo;
    const ushort_t* aptr = ksel + ((size_t)bh * NSEQ + col) * 16 + (g & 1) * 8
                         + (size_t)w * (512 * 16);
    const ushort_t* vp = vt + ((size_t)bh * 16 + col) * NSEQ + w * 512;

    // ---- Phase 1: max over this wave's 512 keys, both subtiles ----
    float m0 = -INFINITY, m1 = -INFINITY;
    const f32x4 z = {0.f, 0.f, 0.f, 0.f};
    bf16x8 pa1[2], pa2[2];
    pa1[0] = *(const bf16x8*)(aptr);
    pa2[0] = *(const bf16x8*)(aptr + 256);
    pa1[1] = *(const bf16x8*)(aptr + 512);
    pa2[1] = *(const bf16x8*)(aptr + 768);
#pragma unroll 2
    for (int kb = 0; kb < 16; ++kb) {
        const bf16x8 c1 = pa1[kb & 1], c2 = pa2[kb & 1];
        const int kn = (kb + 2) & 15;          // wrap: reloads kb 0,1 at the end
        pa1[kb & 1] = *(const bf16x8*)(aptr + (size_t)kn * 512);
        pa2[kb & 1] = *(const bf16x8*)(aptr + (size_t)kn * 512 + 256);
        const f32x4 s1 = __builtin_amdgcn_mfma_f32_16x16x32_bf16(c1, bq1[0], z, 0, 0, 0);
        const f32x4 s2 = __builtin_amdgcn_mfma_f32_16x16x32_bf16(c2, bq1[0], z, 0, 0, 0);
        const f32x4 s3 = __builtin_amdgcn_mfma_f32_16x16x32_bf16(c1, bq1[1], z, 0, 0, 0);
        const f32x4 s4 = __builtin_amdgcn_mfma_f32_16x16x32_bf16(c2, bq1[1], z, 0, 0, 0);
        m0 = fmaxf(m0, fmaxf(fmaxf(s1[0], s1[1]), fmaxf(s1[2], s1[3])));
        m0 = fmaxf(m0, fmaxf(fmaxf(s2[0], s2[1]), fmaxf(s2[2], s2[3])));
        m1 = fmaxf(m1, fmaxf(fmaxf(s3[0], s3[1]), fmaxf(s3[2], s3[3])));
        m1 = fmaxf(m1, fmaxf(fmaxf(s4[0], s4[1]), fmaxf(s4[2], s4[3])));
    }
    m0 = fmaxf(m0, __shfl_xor(m0, 16)); m0 = fmaxf(m0, __shfl_xor(m0, 32));
    m1 = fmaxf(m1, __shfl_xor(m1, 16)); m1 = fmaxf(m1, __shfl_xor(m1, 32));
    if (l < 32) lds_m[w][l] = (l < 16) ? m0 : m1;
    __syncthreads();
    const float mf0 = fmaxf(fmaxf(lds_m[0][col],      lds_m[1][col]),
                            fmaxf(lds_m[2][col],      lds_m[3][col]));
    const float mf1 = fmaxf(fmaxf(lds_m[0][col + 16], lds_m[1][col + 16]),
                            fmaxf(lds_m[2][col + 16], lds_m[3][col + 16]));
    const f32x4 zin0 = {-mf0, -mf0, -mf0, -mf0};
    const f32x4 zin1 = {-mf1, -mf1, -mf1, -mf1};

    // ---- Phase 2: exp-sum + PV (pa slots already hold kb=0,1) ----
    f32x4 o0 = {0.f,0.f,0.f,0.f}, o1 = {0.f,0.f,0.f,0.f};
    float ls0 = 0.f, ls1 = 0.f;
    f16x4 pv1[2], pv2[2];
    pv1[0] = *(const f16x4*)(vp + g * 4);
    pv2[0] = *(const f16x4*)(vp + 16 + g * 4);
    pv1[1] = *(const f16x4*)(vp + 32 + g * 4);
    pv2[1] = *(const f16x4*)(vp + 48 + g * 4);

#pragma unroll 2
    for (int kb = 0; kb < 16; ++kb) {
        const bf16x8 c1 = pa1[kb & 1], c2 = pa2[kb & 1];
        const f16x4 v1 = pv1[kb & 1], v2 = pv2[kb & 1];
        const int kn = (kb + 2) & 15;
        pa1[kb & 1] = *(const bf16x8*)(aptr + (size_t)kn * 512);
        pa2[kb & 1] = *(const bf16x8*)(aptr + (size_t)kn * 512 + 256);
        pv1[kb & 1] = *(const f16x4*)(vp + kn * 32 + g * 4);
        pv2[kb & 1] = *(const f16x4*)(vp + kn * 32 + 16 + g * 4);

        // subtile 0
        {
            f32x4 st1 = __builtin_amdgcn_mfma_f32_16x16x32_bf16(c1, bq2[0], zin0, 0, 0, 0);
            st1       = __builtin_amdgcn_mfma_f32_16x16x32_bf16(c1, bq1[0], st1, 0, 0, 0);
            f32x4 st2 = __builtin_amdgcn_mfma_f32_16x16x32_bf16(c2, bq2[0], zin0, 0, 0, 0);
            st2       = __builtin_amdgcn_mfma_f32_16x16x32_bf16(c2, bq1[0], st2, 0, 0, 0);
            const float p0 = exp2_fast(st1[0]), p1 = exp2_fast(st1[1]);
            const float p2 = exp2_fast(st1[2]), p3 = exp2_fast(st1[3]);
            const float p4 = exp2_fast(st2[0]), p5 = exp2_fast(st2[1]);
            const float p6 = exp2_fast(st2[2]), p7 = exp2_fast(st2[3]);
            ls0 += ((p0 + p1) + (p2 + p3)) + ((p4 + p5) + (p6 + p7));
            H4 b1u, b2u;
            b1u.h2[0] = __builtin_amdgcn_cvt_pkrtz(p0, p1);
            b1u.h2[1] = __builtin_amdgcn_cvt_pkrtz(p2, p3);
            b2u.h2[0] = __builtin_amdgcn_cvt_pkrtz(p4, p5);
            b2u.h2[1] = __builtin_amdgcn_cvt_pkrtz(p6, p7);
            o0 = __builtin_amdgcn_mfma_f32_16x16x16f16(v1, b1u.v, o0, 0, 0, 0);
            o0 = __builtin_amdgcn_mfma_f32_16x16x16f16(v2, b2u.v, o0, 0, 0, 0);
        }
        // subtile 1
        {
            f32x4 st1 = __builtin_amdgcn_mfma_f32_16x16x32_bf16(c1, bq2[1], zin1, 0, 0, 0);
            st1       = __builtin_amdgcn_mfma_f32_16x16x32_bf16(c1, bq1[1], st1, 0, 0, 0);
            f32x4 st2 = __builtin_amdgcn_mfma_f32_16x16x32_bf16(c2, bq2[1], zin1, 0, 0, 0);
            st2       = __builtin_amdgcn_mfma_f32_16x16x32_bf16(c2, bq1[1], st2, 0, 0, 0);
            const float p0 = exp2_fast(st1[0]), p1 = exp2_fast(st1[1]);
            const float p2 = exp2_fast(st1[2]), p3 = exp2_fast(st1[3]);
            const float p4 = exp2_fast(st2[0]), p5 = exp2_fast(st2[1]);
            const float p6 = exp2_fast(st2[2]), p7 = exp2_fast(st2[3]);
            ls1 += ((p0 + p1) + (p2 + p3)) + ((p4 + p5) + (p6 + p7));
            H4 b1u, b2u;
            b1u.h2[0] = __builtin_amdgcn_cvt_pkrtz(p0, p1);
            b1u.h2[1] = __builtin_amdgcn_cvt_pkrtz(p2, p3);
            b2u.h2[0] = __builtin_amdgcn_cvt_pkrtz(p4, p5);
            b2u.h2[1] = __builtin_amdgcn_cvt_pkrtz(p6, p7);
            o1 = __builtin_amdgcn_mfma_f32_16x16x16f16(v1, b1u.v, o1, 0, 0, 0);
            o1 = __builtin_amdgcn_mfma_f32_16x16x16f16(v2, b2u.v, o1, 0, 0, 0);
        }
    }

    ls0 += __shfl_xor(ls0, 16); ls0 += __shfl_xor(ls0, 32);
    ls1 += __shfl_xor(ls1, 16); ls1 += __shfl_xor(ls1, 32);

    // ---- Combine the four key-quarters (exact: same m) ----
    if (w > 0) {
        *(f32x4*)&lds_o[w - 1][0][col][4 * g] = o0;
        *(f32x4*)&lds_o[w - 1][1][col][4 * g] = o1;
        if (l < 32) lds_l[w - 1][l >> 4][col] = (l < 16) ? ls0 : ls1;
    }
    __syncthreads();
    if (w == 0) {
        const int b = bh >> 3, h = bh & 7;
#pragma unroll
        for (int s = 0; s < 2; ++s) {
            f32x4 oa = s ? o1 : o0;
            float lt = s ? ls1 : ls0;
#pragma unroll
            for (int j = 0; j < 3; ++j) {
                const f32x4 ob = *(const f32x4*)&lds_o[j][s][col][4 * g];
                oa[0] += ob[0]; oa[1] += ob[1]; oa[2] += ob[2]; oa[3] += ob[3];
                lt += lds_l[j][s][col];
            }
            const float li = 1.0f / lt;
            uint2 pkd;
            pkd.x = pk2(oa[0] * li, oa[1] * li);
            pkd.y = pk2(oa[2] * li, oa[3] * li);
            *(uint2*)(ctxb + ((size_t)(b * NSEQ + qbase + s * 16 + col)) * 128
                      + h * 16 + 4 * g) = pkd;
        }
    }
}

// ---------------------------------------------------------------------------
// Kernel 3: output projection on MFMA (packed split-bf16 Wo).
// 512 single-wave blocks: wave -> 16 rows.
// ---------------------------------------------------------------------------
__global__ __launch_bounds__(64) void outproj_kernel(
    const ushort_t* __restrict__ ctxb,
    const ushort_t* __restrict__ wo_hi, const ushort_t* __restrict__ wo_lo,
    const float* __restrict__ bo, float* __restrict__ out)
{
    const int l   = threadIdx.x;
    const int col = l & 15;
    const int g   = l >> 4;
    const int row0 = blockIdx.x * 16;

    const float bval = bo[col];
    f32x4 acc = {bval, bval, bval, bval};
    const ushort_t* ar = ctxb + (size_t)(row0 + col) * 128 + g * 8;
#pragma unroll
    for (int f = 0; f < 4; ++f) {
        const bf16x8 a = *(const bf16x8*)(ar + f * 32);
        const size_t o = ((size_t)f * 64 + l) * 8;
        const bf16x8 bh_ = *(const bf16x8*)(wo_hi + o);
        const bf16x8 bl_ = *(const bf16x8*)(wo_lo + o);
        acc = __builtin_amdgcn_mfma_f32_16x16x32_bf16(a, bh_, acc, 0, 0, 0);
        acc = __builtin_amdgcn_mfma_f32_16x16x32_bf16(a, bl_, acc, 0, 0, 0);
    }
#pragma unroll
    for (int r = 0; r < 4; ++r)
        out[(size_t)(row0 + 4 * g + r) * 16 + col] = acc[r];
}

// ---------------------------------------------------------------------------
extern "C" void kernel_launch(void* const* d_in, const int* in_sizes, int n_in,
                              void* d_out, int out_size, void* d_ws, size_t ws_size,
                              hipStream_t stream)
{
    const float* query = (const float*)d_in[0];
    const float* key_  = (const float*)d_in[1];
    const float* value = (const float*)d_in[2];
    const float* Wq = (const float*)d_in[3];
    const float* bq = (const float*)d_in[4];
    const float* Wk = (const float*)d_in[5];
    const float* bk = (const float*)d_in[6];
    const float* Wv = (const float*)d_in[7];
    const float* bv = (const float*)d_in[8];
    const float* Wo = (const float*)d_in[9];
    const float* bo = (const float*)d_in[10];
    float* out = (float*)d_out;

    ushort_t* base = (ushort_t*)d_ws;
    ushort_t* q_hi = base;
    ushort_t* q_lo = base + (1u << 20);
    ushort_t* k_hi = base + (2u << 20);
    ushort_t* k_lo = base + (3u << 20);
    ushort_t* vt   = base + (4u << 20);
    ushort_t* ctxb = base + (5u << 20);
    ushort_t* wpk_hi = base + (6u << 20);
    ushort_t* wpk_lo = wpk_hi + 32768;
    ushort_t* wo_hi  = wpk_hi + 65536;
    ushort_t* wo_lo  = wo_hi + 2048;

    wpack_kernel<<<dim3(17), dim3(256), 0, stream>>>(
        Wq, Wk, Wo, wpk_hi, wpk_lo, wo_hi, wo_lo);
    qkv_proj_kernel<<<dim3(2560), dim3(256), 0, stream>>>(
        query, key_, value, bq, bk, Wv, bv, wpk_hi, wpk_lo,
        q_hi, q_lo, k_hi, k_lo, vt);
    attn_kernel<<<dim3(2048), dim3(256), 0, stream>>>(
        q_hi, q_lo, k_hi, k_lo, vt, ctxb);
    outproj_kernel<<<dim3(512), dim3(64), 0, stream>>>(
        ctxb, wo_hi, wo_lo, bo, out);
}